// Round 7
// baseline (1001.584 us; speedup 1.0000x reference)
//
#include <hip/hip_runtime.h>
#include <math.h>

#define D_ 512
#define H_ 8

typedef short bf16x8 __attribute__((ext_vector_type(8)));
typedef float f32x4 __attribute__((ext_vector_type(4)));

struct Outs { void* p[5]; };

__device__ __forceinline__ unsigned short f2bf(float x) {
  unsigned int u = __float_as_uint(x);
  unsigned int r = (u + 0x7fff + ((u >> 16) & 1)) >> 16;
  return (unsigned short)r;
}
__device__ __forceinline__ float bf2f(unsigned short b) {
  return __uint_as_float(((unsigned int)b) << 16);
}

// ---------------- utility ----------------
__global__ void fill_kernel(float* __restrict__ p, float v, long n) {
  long i = (long)blockIdx.x * blockDim.x + threadIdx.x;
  long st = (long)gridDim.x * blockDim.x;
  for (; i < n; i += st) p[i] = v;
}

__global__ void convert_bf16_kernel(const float* __restrict__ in,
                                    unsigned short* __restrict__ out, long n8) {
  long i = (long)blockIdx.x * blockDim.x + threadIdx.x;
  long st = (long)gridDim.x * blockDim.x;
  for (; i < n8; i += st) {
    float4 a = ((const float4*)in)[i * 2];
    float4 b = ((const float4*)in)[i * 2 + 1];
    bf16x8 o;
    o[0] = (short)f2bf(a.x); o[1] = (short)f2bf(a.y);
    o[2] = (short)f2bf(a.z); o[3] = (short)f2bf(a.w);
    o[4] = (short)f2bf(b.x); o[5] = (short)f2bf(b.y);
    o[6] = (short)f2bf(b.z); o[7] = (short)f2bf(b.w);
    ((bf16x8*)out)[i] = o;
  }
}

// Wt[n][k] = bf16(W[k][n]) for a 512x512 matrix
__global__ void transpose_bf16_kernel(const float* __restrict__ W,
                                      unsigned short* __restrict__ Wt) {
  int n = blockIdx.x;
  int k = threadIdx.x;
  Wt[(long)n * D_ + k] = f2bf(W[(long)k * D_ + n]);
}

__global__ void copy_bias_kernel(const float* __restrict__ in,
                                 float* __restrict__ out) {
  out[threadIdx.x] = in[threadIdx.x];
}

// ---------------- fused weight precompute (transposed bf16 out) ----------------
__global__ void fuse_weight_kernel(const float* __restrict__ Win,
                                   const float* __restrict__ bin,
                                   const float* __restrict__ rel,
                                   unsigned short* __restrict__ Wf,
                                   float* __restrict__ bf) {
  int row = blockIdx.x;            // 0..512 (c index; 512 => bias)
  int j = threadIdx.x;             // 0..511 (h*64+e)
  int h = j >> 6, e = j & 63;
  const float* src = (row < D_) ? (Win + (long)row * D_) : bin;
  const float* rl = rel + h * 64 * 64;
  float acc = 0.f;
#pragma unroll 16
  for (int d = 0; d < 64; ++d) acc = fmaf(src[h * 64 + d], rl[d * 64 + e], acc);
  if (row < D_) Wf[(long)j * D_ + row] = f2bf(acc);
  else bf[j] = acc;
}

// ---------------- CSR build: hist -> scan -> scatter ----------------
__global__ void hist_kernel(const int* __restrict__ w_dst,
                            const int* __restrict__ c_dst,
                            const int* __restrict__ b_dst,
                            int* __restrict__ degree, int E, int NP) {
  int i = blockIdx.x * blockDim.x + threadIdx.x;
  if (i >= 3 * E) return;
  int r = i / E, e = i - r * E;
  int d, base;
  if (r == 0)      { d = w_dst[e]; base = 0; }
  else if (r == 1) { d = c_dst[e]; base = NP; }
  else             { d = b_dst[e]; base = 2 * NP; }
  atomicAdd(degree + base + d, 1);
}

__global__ void scan1_kernel(const int* __restrict__ in, int* __restrict__ out,
                             int* __restrict__ aux, int n) {
  __shared__ int tmp[256];
  int t = threadIdx.x;
  int i = blockIdx.x * 256 + t;
  int v = (i < n) ? in[i] : 0;
  tmp[t] = v;
  __syncthreads();
#pragma unroll
  for (int d = 1; d < 256; d <<= 1) {
    int add = (t >= d) ? tmp[t - d] : 0;
    __syncthreads();
    tmp[t] += add;
    __syncthreads();
  }
  if (i < n) out[i] = tmp[t] - v;   // exclusive
  if (t == 255) aux[blockIdx.x] = tmp[255];
}

__global__ void scan2_kernel(int* __restrict__ aux, int nb) {
  __shared__ int tmp[1024];
  int t = threadIdx.x;
  int v = (t < nb) ? aux[t] : 0;
  tmp[t] = v;
  __syncthreads();
#pragma unroll
  for (int d = 1; d < 1024; d <<= 1) {
    int add = (t >= d) ? tmp[t - d] : 0;
    __syncthreads();
    tmp[t] += add;
    __syncthreads();
  }
  if (t < nb) aux[t] = tmp[t] - v;  // exclusive block offsets
}

__global__ void scan3_kernel(int* __restrict__ starts, int* __restrict__ cursor,
                             const int* __restrict__ aux, int n) {
  int i = blockIdx.x * 256 + threadIdx.x;
  if (i >= n) return;
  int s = starts[i] + aux[blockIdx.x];
  starts[i] = s;
  cursor[i] = s;
}

__global__ void scatter_kernel(const int* __restrict__ w_src, const int* __restrict__ w_dst,
                               const int* __restrict__ c_src, const int* __restrict__ c_dst,
                               const int* __restrict__ b_src, const int* __restrict__ b_dst,
                               int* __restrict__ cursor, int* __restrict__ csr,
                               int E, int NP) {
  int i = blockIdx.x * blockDim.x + threadIdx.x;
  if (i >= 3 * E) return;
  int r = i / E, e = i - r * E;
  int s, d, base;
  if (r == 0)      { s = w_src[e]; d = w_dst[e]; base = 0; }
  else if (r == 1) { s = c_src[e]; d = c_dst[e]; base = NP; }
  else             { s = b_src[e]; d = b_dst[e]; base = 2 * NP; }
  int pos = atomicAdd(cursor + base + d, 1);
  csr[pos] = s;
}

// ---------------- fused per-node edge attention (flash-style) ----------------
template <int TWO_LISTS>
__global__ __launch_bounds__(256) void attn_kernel(
    const unsigned short* __restrict__ q,
    const unsigned short* __restrict__ k0, const unsigned short* __restrict__ v0,
    const unsigned short* __restrict__ k1, const unsigned short* __restrict__ v1,
    const int* __restrict__ csr, const int* __restrict__ starts,
    const int* __restrict__ degree, int base0, int base1,
    const float* __restrict__ pri, int poff0, int poff1,
    unsigned short* __restrict__ out, int n_nodes, float outscale) {
  int gw = (int)(((long)blockIdx.x * blockDim.x + threadIdx.x) >> 6);
  if (gw >= n_nodes) return;
  int lane = threadIdx.x & 63;
  int h = lane >> 3, off = (lane & 7) << 3;
  const long rowoff = (long)gw * D_ + h * 64 + off;
  bf16x8 qv = *(const bf16x8*)(q + rowoff);
  float qf[8];
#pragma unroll
  for (int r = 0; r < 8; ++r) qf[r] = bf2f((unsigned short)qv[r]);

  float res[8] = {};

  auto process = [&](const unsigned short* K, const unsigned short* V,
                     int base, float ps) {
    int st = starts[base + gw], dg = degree[base + gw];
    float m = -INFINITY, l = 0.f;
    float acc[8] = {};
    for (int i = 0; i < dg; ++i) {
      int s = csr[st + i];
      const long ro = (long)s * D_ + h * 64 + off;
      bf16x8 kv = *(const bf16x8*)(K + ro);
      bf16x8 vv = *(const bf16x8*)(V + ro);
      float dot = 0.f;
#pragma unroll
      for (int r = 0; r < 8; ++r)
        dot = fmaf(qf[r], bf2f((unsigned short)kv[r]), dot);
      dot += __shfl_xor(dot, 1);
      dot += __shfl_xor(dot, 2);
      dot += __shfl_xor(dot, 4);
      float sc = dot * ps;
      float mn = fmaxf(m, sc);
      float scale = __expf(m - mn);   // m=-inf first edge -> 0
      float p = __expf(sc - mn);
      l = l * scale + p;
#pragma unroll
      for (int r = 0; r < 8; ++r)
        acc[r] = acc[r] * scale + p * bf2f((unsigned short)vv[r]);
      m = mn;
    }
    if (l > 0.f) {
      float inv = 1.f / l;
#pragma unroll
      for (int r = 0; r < 8; ++r) res[r] += acc[r] * inv;
    }
  };

  process(k0, v0, base0, pri[poff0 + h] * 0.125f);
  if (TWO_LISTS) process(k1, v1, base1, pri[poff1 + h] * 0.125f);

  bf16x8 o;
#pragma unroll
  for (int r = 0; r < 8; ++r) o[r] = (short)f2bf(res[r] * outscale);
  *(bf16x8*)(out + rowoff) = o;
}

// ---------------- MFMA GEMM: 256x256 tile, 16-phase K-half pipeline ----------
// Phase s (0..15) consumes K-half s (tile s>>1, half s&1) and stages K-half
// s+3 inside the phase (T14 issue-early). LDS: [A|B][dbuf][khalf][256][32]
// (64B rows), 128 KiB. vmcnt(8) steady (3 K-halves in flight), 4/0 at the
// tail, one barrier per phase, never a mid-loop drain. Bank swizzle:
// slot = q ^ (rr&3) ^ ((rr>>2)&3) applied to global source AND ds_read.
__device__ __forceinline__ void gload_lds16(const void* g, void* l) {
  __builtin_amdgcn_global_load_lds(
      (const __attribute__((address_space(1))) void*)g,
      (__attribute__((address_space(3))) void*)l, 16, 0, 0);
}

template <int OUT_BF16, int WITH_SKIP>
__global__ __launch_bounds__(512, 2) void gemm_mfma(
    const unsigned short* __restrict__ A,
    const unsigned short* __restrict__ Bt,
    const float* __restrict__ bias,
    Outs outs, int M, int GX, float a_scale,
    const float* __restrict__ Hres,
    const float* __restrict__ skip, int skip_idx) {
  __shared__ unsigned short AsmL[4 * 8192];   // [dbuf*2+khalf][256][32] 64 KiB
  __shared__ unsigned short BsmL[4 * 8192];   // 64 KiB

  // bijective XCD-aware swizzle (m204); N-tile fastest within a chunk.
  const int nwg = gridDim.x;
  const int orig = blockIdx.x;
  const int q8 = nwg >> 3, r8 = nwg & 7;
  const int xcd = orig & 7, pos = orig >> 3;
  const int wgid =
      (xcd < r8 ? xcd * (q8 + 1) : r8 * (q8 + 1) + (xcd - r8) * q8) + pos;
  const int bm = (wgid / GX) * 256;
  const int bn = (wgid % GX) * 256;

  const int tid = threadIdx.x;                  // 0..511
  const int wave = tid >> 6, lane = tid & 63;
  const int wm = (wave >> 2) * 128;             // 2 M-waves
  const int wn = (wave & 3) * 64;               // 4 N-waves

  // staging thread map: row = tid>>2 (+128/round), 16B chunk = tid&3
  const int srow = tid >> 2;                    // 0..127
  const int schk = tid & 3;
  const int sf = ((tid >> 2) & 3) ^ ((tid >> 4) & 3);   // row swizzle key
  const int scg = ((schk ^ sf) << 3);           // swizzled global col (elems)

  // read-side: lane rr reads its row's swizzled 16B slot
  const int rr = lane & 15;
  const int qk = lane >> 4;                     // k-chunk 0..3
  const int slotx = ((qk ^ (rr & 3) ^ ((rr >> 2) & 3)) << 4);  // byte slot

  f32x4 acc[8][4] = {};

  // stage K-half u (u = tile*2 + kh): 4 global_load_lds per thread
  auto STAGE_U = [&](int u) {
    const int tile = u >> 1, kh = u & 1;
    const int slot = ((tile & 1) * 2 + kh);
    const int k0 = tile * 64 + kh * 32 + scg;
#pragma unroll
    for (int rd = 0; rd < 2; ++rd) {
      int gr = bm + srow + rd * 128;
      if (gr >= M) gr = M - 1;  // clamp: feeds only unstored C rows
      gload_lds16(A + (long)gr * D_ + k0,
                  AsmL + slot * 8192 + rd * 4096 + wave * 512);
    }
#pragma unroll
    for (int rd = 0; rd < 2; ++rd) {
      int gr = bn + srow + rd * 128;
      gload_lds16(Bt + (long)gr * D_ + k0,
                  BsmL + slot * 8192 + rd * 4096 + wave * 512);
    }
  };

  // prologue: K-halves 0,1,2 (12 loads/thread in flight)
  STAGE_U(0);
  STAGE_U(1);
  STAGE_U(2);

#pragma unroll
  for (int s = 0; s < 16; ++s) {
    // wait for K-half s's 4 loads; keep later K-halves in flight
    if (s <= 13)      asm volatile("s_waitcnt vmcnt(8)" ::: "memory");
    else if (s == 14) asm volatile("s_waitcnt vmcnt(4)" ::: "memory");
    else              asm volatile("s_waitcnt vmcnt(0)" ::: "memory");
    __builtin_amdgcn_s_barrier();
    asm volatile("" ::: "memory");

    const int tile = s >> 1, kh = s & 1;
    const int slot = ((tile & 1) * 2 + kh);
    const char* ab = (const char*)AsmL + slot * 16384;
    const char* bb = (const char*)BsmL + slot * 16384;

    bf16x8 af[8], bfr[4];
#pragma unroll
    for (int mi = 0; mi < 8; ++mi)
      af[mi] = *(const bf16x8*)(ab + (wm + mi * 16 + rr) * 64 + slotx);
#pragma unroll
    for (int nj = 0; nj < 4; ++nj)
      bfr[nj] = *(const bf16x8*)(bb + (wn + nj * 16 + rr) * 64 + slotx);

    if (s + 3 <= 15) STAGE_U(s + 3);   // issue-early: hides under MFMA

    __builtin_amdgcn_s_setprio(1);
#pragma unroll
    for (int mi = 0; mi < 8; ++mi)
#pragma unroll
      for (int nj = 0; nj < 4; ++nj)
        acc[mi][nj] = __builtin_amdgcn_mfma_f32_16x16x32_bf16(
            af[mi], bfr[nj], acc[mi][nj], 0, 0, 0);
    __builtin_amdgcn_s_setprio(0);
    asm volatile("" ::: "memory");
  }

  // epilogue
  float alpha = 1.f, beta = 0.f;
  if (WITH_SKIP) {
    float sv = skip[skip_idx];
    alpha = 1.f / (1.f + expf(-sv));
    beta = 1.f - alpha;
  }
  const int cr = (lane >> 4) * 4;
  const int cc = lane & 15;
  const int matu = (bn + wn) >> 9;
  const int wcb = (bn + wn) & 511;
  unsigned short* ob16 = (unsigned short*)outs.p[matu];
  float* ob32 = (float*)outs.p[0];
#pragma unroll
  for (int mi = 0; mi < 8; ++mi) {
    int rowb = bm + wm + mi * 16 + cr;
#pragma unroll
    for (int nj = 0; nj < 4; ++nj) {
      int col = bn + wn + nj * 16 + cc;
      float bb2 = bias[col];
#pragma unroll
      for (int r = 0; r < 4; ++r) {
        int row = rowb + r;
        if (row >= M) continue;
        float val = acc[mi][nj][r] * a_scale + bb2;
        if (WITH_SKIP) val = val * alpha + Hres[(long)row * D_ + col] * beta;
        if (OUT_BF16)
          ob16[(long)row * D_ + wcb + nj * 16 + cc] = f2bf(val);
        else
          ob32[(long)row * D_ + col] = val;
      }
    }
  }
}

// ---------------- launch ----------------
extern "C" void kernel_launch(void* const* d_in, const int* in_sizes, int n_in,
                              void* d_out, int out_size, void* d_ws, size_t ws_size,
                              hipStream_t stream) {
  const float* h_author = (const float*)d_in[0];
  const float* h_paper  = (const float*)d_in[1];
  const int* w_src = (const int*)d_in[2];
  const int* w_dst = (const int*)d_in[3];
  const int* c_src = (const int*)d_in[4];
  const int* c_dst = (const int*)d_in[5];
  const int* b_src = (const int*)d_in[6];
  const int* b_dst = (const int*)d_in[7];
  const float* Wk = (const float*)d_in[8];
  const float* bk = (const float*)d_in[9];
  const float* Wq = (const float*)d_in[10];
  const float* bq = (const float*)d_in[11];
  const float* Wv = (const float*)d_in[12];
  const float* bv = (const float*)d_in[13];
  const float* Wa = (const float*)d_in[14];
  const float* ba = (const float*)d_in[15];
  const float* rel_att = (const float*)d_in[16];
  const float* rel_msg = (const float*)d_in[17];
  const float* rel_pri = (const float*)d_in[18];
  const float* skip = (const float*)d_in[19];

  const int NA = in_sizes[0] / D_;
  const int NP = in_sizes[1] / D_;
  const int E  = in_sizes[2];
  const long nmax = (NA > NP) ? NA : NP;
  const int NT = 2 * NP + NA;        // concatenated CSR node count

  char* w = (char*)d_ws;
  auto alloc = [&](long bytes) {
    char* p = w;
    w += (bytes + 255) & ~255L;
    return p;
  };
  unsigned short* hA16 = (unsigned short*)alloc((long)NA * D_ * 2);
  unsigned short* hP16 = (unsigned short*)alloc((long)NP * D_ * 2);
  unsigned short* Pq   = (unsigned short*)alloc((long)NP * D_ * 2);
  unsigned short* Pkc  = (unsigned short*)alloc((long)NP * D_ * 2);
  unsigned short* Pvc  = (unsigned short*)alloc((long)NP * D_ * 2);
  unsigned short* Pkb  = (unsigned short*)alloc((long)NP * D_ * 2);
  unsigned short* Pvb  = (unsigned short*)alloc((long)NP * D_ * 2);
  unsigned short* Aq   = (unsigned short*)alloc((long)NA * D_ * 2);
  unsigned short* Akw  = (unsigned short*)alloc((long)NA * D_ * 2);
  unsigned short* Avw  = (unsigned short*)alloc((long)NA * D_ * 2);
  unsigned short* t16  = (unsigned short*)alloc(nmax * D_ * 2);
  unsigned short* BtP  = (unsigned short*)alloc((long)2560 * D_ * 2);
  unsigned short* BtA  = (unsigned short*)alloc((long)1536 * D_ * 2);
  float* bfP           = (float*)alloc(2560 * 4);
  float* bfA           = (float*)alloc(1536 * 4);
  unsigned short* Wa0t = (unsigned short*)alloc((long)D_ * D_ * 2);
  unsigned short* Wa1t = (unsigned short*)alloc((long)D_ * D_ * 2);
  int* degree          = (int*)alloc((long)NT * 4);
  int* starts          = (int*)alloc((long)NT * 4);
  int* cursor          = (int*)alloc((long)NT * 4);
  int* csr             = (int*)alloc((long)3 * E * 4);
  int* aux             = (int*)alloc(((long)NT / 256 + 2) * 4);

  const long WD = (long)D_ * D_;
  const long RS = (long)H_ * 64 * 64;
  const long SEG = (long)D_ * D_;

  auto fill = [&](float* p, float v, long n) {
    long b = (n + 255) / 256;
    int blocks = (int)(b > 4096 ? 4096 : b);
    fill_kernel<<<blocks, 256, 0, stream>>>(p, v, n);
  };
  auto cvt = [&](const float* in, unsigned short* out, long n) {
    long n8 = n / 8;
    long b = (n8 + 255) / 256;
    int blocks = (int)(b > 2048 ? 2048 : b);
    convert_bf16_kernel<<<blocks, 256, 0, stream>>>(in, out, n8);
  };

  float* out_a = (float*)d_out;
  float* out_p = out_a + (long)NA * D_;

  // ---- one-time conversions ----
  cvt(h_author, hA16, (long)NA * D_);
  cvt(h_paper, hP16, (long)NP * D_);

  // ---- CSR build (all 3 relations concatenated; papers x2, authors x1) ----
  fill((float*)degree, 0.f, NT);  // bit-pattern zero
  {
    int th = 3 * E;
    hist_kernel<<<(th + 255) / 256, 256, 0, stream>>>(w_dst, c_dst, b_dst,
                                                      degree, E, NP);
    int nb = (NT + 255) / 256;
    scan1_kernel<<<nb, 256, 0, stream>>>(degree, starts, aux, NT);
    scan2_kernel<<<1, 1024, 0, stream>>>(aux, nb);
    scan3_kernel<<<nb, 256, 0, stream>>>(starts, cursor, aux, NT);
    scatter_kernel<<<(th + 255) / 256, 256, 0, stream>>>(
        w_src, w_dst, c_src, c_dst, b_src, b_dst, cursor, csr, E, NP);
  }

  // ---- build fused Bt for papers: [q_p | k_cites | v_cites | k_wb | v_wb] ----
  transpose_bf16_kernel<<<D_, D_, 0, stream>>>(Wq + WD, BtP);
  copy_bias_kernel<<<1, D_, 0, stream>>>(bq + D_, bfP);
  fuse_weight_kernel<<<513, 512, 0, stream>>>(Wk + WD, bk + D_, rel_att + RS,
                                              BtP + SEG, bfP + 512);
  fuse_weight_kernel<<<513, 512, 0, stream>>>(Wv + WD, bv + D_, rel_msg + RS,
                                              BtP + 2 * SEG, bfP + 1024);
  fuse_weight_kernel<<<513, 512, 0, stream>>>(Wk + WD, bk + D_, rel_att + 2 * RS,
                                              BtP + 3 * SEG, bfP + 1536);
  fuse_weight_kernel<<<513, 512, 0, stream>>>(Wv + WD, bv + D_, rel_msg + 2 * RS,
                                              BtP + 4 * SEG, bfP + 2048);

  // ---- fused Bt for authors: [q_a | k_writes | v_writes] ----
  transpose_bf16_kernel<<<D_, D_, 0, stream>>>(Wq, BtA);
  copy_bias_kernel<<<1, D_, 0, stream>>>(bq, bfA);
  fuse_weight_kernel<<<513, 512, 0, stream>>>(Wk, bk, rel_att,
                                              BtA + SEG, bfA + 512);
  fuse_weight_kernel<<<513, 512, 0, stream>>>(Wv, bv, rel_msg,
                                              BtA + 2 * SEG, bfA + 1024);

  // output-projection weights
  transpose_bf16_kernel<<<D_, D_, 0, stream>>>(Wa, Wa0t);
  transpose_bf16_kernel<<<D_, D_, 0, stream>>>(Wa + WD, Wa1t);

  // ---- fused projection GEMMs (256x256 tiles, 16-phase pipeline) ----
  {
    Outs o; o.p[0] = Pq; o.p[1] = Pkc; o.p[2] = Pvc; o.p[3] = Pkb; o.p[4] = Pvb;
    int gy = (NP + 255) / 256;
    gemm_mfma<1, 0><<<10 * gy, 512, 0, stream>>>(
        hP16, BtP, bfP, o, NP, 10, 1.f, nullptr, nullptr, 0);
  }
  {
    Outs o; o.p[0] = Aq; o.p[1] = Akw; o.p[2] = Avw; o.p[3] = Aq; o.p[4] = Aq;
    int gy = (NA + 255) / 256;
    gemm_mfma<1, 0><<<6 * gy, 512, 0, stream>>>(
        hA16, BtA, bfA, o, NA, 6, 1.f, nullptr, nullptr, 0);
  }

  // ---- paper attention: writes (k/v from authors) + cites (k/v from papers) ----
  {
    long th = (long)NP * 64;
    attn_kernel<1><<<(int)((th + 255) / 256), 256, 0, stream>>>(
        Pq, Akw, Avw, Pkc, Pvc, csr, starts, degree, 0, NP,
        rel_pri, 0, H_, t16, NP, 0.5f);
  }
  // ---- paper output ----
  {
    Outs o; o.p[0] = out_p; o.p[1] = o.p[2] = o.p[3] = o.p[4] = out_p;
    int gy = (NP + 255) / 256;
    gemm_mfma<0, 1><<<2 * gy, 512, 0, stream>>>(
        t16, Wa1t, ba + D_, o, NP, 2, 1.f, h_paper, skip, 1);
  }

  // ---- author attention: written_by (k/v from papers) ----
  {
    long th = (long)NA * 64;
    attn_kernel<0><<<(int)((th + 255) / 256), 256, 0, stream>>>(
        Aq, Pkb, Pvb, Pkb, Pvb, csr, starts, degree, 2 * NP, 2 * NP,
        rel_pri, 2 * H_, 2 * H_, t16, NA, 1.f);
  }
  // ---- author output ----
  {
    Outs o; o.p[0] = out_a; o.p[1] = o.p[2] = o.p[3] = o.p[4] = out_a;
    int gy = (NA + 255) / 256;
    gemm_mfma<0, 1><<<2 * gy, 512, 0, stream>>>(
        t16, Wa0t, ba, o, NA, 2, 1.f, h_author, skip, 0);
  }
}

// Round 8
// 918.967 us; speedup vs baseline: 1.0899x; 1.0899x over previous
//
#include <hip/hip_runtime.h>
#include <math.h>

#define D_ 512
#define H_ 8

typedef short bf16x8 __attribute__((ext_vector_type(8)));
typedef float f32x4 __attribute__((ext_vector_type(4)));

__device__ __forceinline__ unsigned short f2bf(float x) {
  unsigned int u = __float_as_uint(x);
  unsigned int r = (u + 0x7fff + ((u >> 16) & 1)) >> 16;
  return (unsigned short)r;
}
__device__ __forceinline__ float bf2f(unsigned short b) {
  return __uint_as_float(((unsigned int)b) << 16);
}

// ================= prep: cvt + fuse-weights + transposes + bias + zero =======
struct PrepArgs {
  const float *hA, *hP;
  unsigned short *hA16, *hP16;
  const float *fWin[6], *fbin[6], *frel[6];
  unsigned short *fWf[6];
  float *fbf[6];
  const float *tW[4];
  unsigned short *tWt[4];
  const float *cin[2];
  float *cout[2];
  int *degree;
  int NT;
  int b1, b2, b3, b4, b5;
};

__global__ __launch_bounds__(512) void prep_kernel(PrepArgs p) {
  const int b = blockIdx.x, t = threadIdx.x;
  if (b < p.b2) {                    // bf16 convert (8 elems/thread)
    const float* in; unsigned short* out; long i;
    if (b < p.b1) { in = p.hA; out = p.hA16; i = (long)b * 512 + t; }
    else          { in = p.hP; out = p.hP16; i = (long)(b - p.b1) * 512 + t; }
    float4 a = ((const float4*)in)[i * 2];
    float4 c = ((const float4*)in)[i * 2 + 1];
    bf16x8 o;
    o[0] = (short)f2bf(a.x); o[1] = (short)f2bf(a.y);
    o[2] = (short)f2bf(a.z); o[3] = (short)f2bf(a.w);
    o[4] = (short)f2bf(c.x); o[5] = (short)f2bf(c.y);
    o[6] = (short)f2bf(c.z); o[7] = (short)f2bf(c.w);
    ((bf16x8*)out)[i] = o;
  } else if (b < p.b3) {             // fused rel-weight: Wf_t[j][row]
    int idx = b - p.b2;
    int job = idx / 513, row = idx - job * 513;
    int h = t >> 6, e = t & 63;
    const float* src = (row < D_) ? (p.fWin[job] + (long)row * D_) : p.fbin[job];
    const float* rl = p.frel[job] + h * 64 * 64;
    float acc = 0.f;
#pragma unroll 16
    for (int d = 0; d < 64; ++d)
      acc = fmaf(src[h * 64 + d], rl[d * 64 + e], acc);
    if (row < D_) p.fWf[job][(long)t * D_ + row] = f2bf(acc);
    else p.fbf[job][t] = acc;
  } else if (b < p.b4) {             // transpose-convert 512x512
    int idx = b - p.b3;
    int job = idx >> 9, n = idx & 511;
    p.tWt[job][(long)n * D_ + t] = f2bf(p.tW[job][(long)t * D_ + n]);
  } else if (b < p.b5) {             // bias copies
    int job = b - p.b4;
    p.cout[job][t] = p.cin[job][t];
  } else {                           // degree zero-fill
    int i = (b - p.b5) * 512 + t;
    if (i < p.NT) p.degree[i] = 0;
  }
}

// ================= CSR build: hist -> scan -> scatter ========================
__global__ void hist_kernel(const int* __restrict__ w_dst,
                            const int* __restrict__ c_dst,
                            const int* __restrict__ b_dst,
                            int* __restrict__ degree, int E, int NP) {
  int i = blockIdx.x * blockDim.x + threadIdx.x;
  if (i >= 3 * E) return;
  int r = i / E, e = i - r * E;
  int d, base;
  if (r == 0)      { d = w_dst[e]; base = 0; }
  else if (r == 1) { d = c_dst[e]; base = NP; }
  else             { d = b_dst[e]; base = 2 * NP; }
  atomicAdd(degree + base + d, 1);
}

__global__ void scan1_kernel(const int* __restrict__ in, int* __restrict__ out,
                             int* __restrict__ aux, int n) {
  __shared__ int tmp[256];
  int t = threadIdx.x;
  int i = blockIdx.x * 256 + t;
  int v = (i < n) ? in[i] : 0;
  tmp[t] = v;
  __syncthreads();
#pragma unroll
  for (int d = 1; d < 256; d <<= 1) {
    int add = (t >= d) ? tmp[t - d] : 0;
    __syncthreads();
    tmp[t] += add;
    __syncthreads();
  }
  if (i < n) out[i] = tmp[t] - v;   // exclusive
  if (t == 255) aux[blockIdx.x] = tmp[255];
}

__global__ void scan2_kernel(int* __restrict__ aux, int nb) {
  __shared__ int tmp[1024];
  int t = threadIdx.x;
  int v = (t < nb) ? aux[t] : 0;
  tmp[t] = v;
  __syncthreads();
#pragma unroll
  for (int d = 1; d < 1024; d <<= 1) {
    int add = (t >= d) ? tmp[t - d] : 0;
    __syncthreads();
    tmp[t] += add;
    __syncthreads();
  }
  if (t < nb) aux[t] = tmp[t] - v;  // exclusive block offsets
}

__global__ void scan3_kernel(int* __restrict__ starts, int* __restrict__ cursor,
                             const int* __restrict__ aux, int n) {
  int i = blockIdx.x * 256 + threadIdx.x;
  if (i >= n) return;
  int s = starts[i] + aux[blockIdx.x];
  starts[i] = s;
  cursor[i] = s;
}

__global__ void scatter_kernel(const int* __restrict__ w_src, const int* __restrict__ w_dst,
                               const int* __restrict__ c_src, const int* __restrict__ c_dst,
                               const int* __restrict__ b_src, const int* __restrict__ b_dst,
                               int* __restrict__ cursor, int* __restrict__ csr,
                               int E, int NP) {
  int i = blockIdx.x * blockDim.x + threadIdx.x;
  if (i >= 3 * E) return;
  int r = i / E, e = i - r * E;
  int s, d, base;
  if (r == 0)      { s = w_src[e]; d = w_dst[e]; base = 0; }
  else if (r == 1) { s = c_src[e]; d = c_dst[e]; base = NP; }
  else             { s = b_src[e]; d = b_dst[e]; base = 2 * NP; }
  int pos = atomicAdd(cursor + base + d, 1);
  csr[pos] = s;
}

// ================= fused per-node edge attention (papers + authors) ==========
__global__ __launch_bounds__(256) void attn_all(
    const unsigned short* __restrict__ Pq,
    const unsigned short* __restrict__ Akw, const unsigned short* __restrict__ Avw,
    const unsigned short* __restrict__ Pkc, const unsigned short* __restrict__ Pvc,
    const unsigned short* __restrict__ Aq,
    const unsigned short* __restrict__ Pkb, const unsigned short* __restrict__ Pvb,
    const int* __restrict__ csr, const int* __restrict__ starts,
    const int* __restrict__ degree, const float* __restrict__ pri,
    unsigned short* __restrict__ t16, int NP, int NA, int NAp) {
  long gid = (long)blockIdx.x * blockDim.x + threadIdx.x;
  int gw = (int)(gid >> 6);
  if (gw >= NP + NAp) return;
  int lane = threadIdx.x & 63;
  int h = lane >> 3, off = (lane & 7) << 3;

  const unsigned short* q;
  long orow;
  int node;
  const int paper = gw < NP;
  if (paper) {
    node = gw; q = Pq;
    orow = (long)(NAp + node) * D_ + h * 64 + off;
  } else {
    int aw = gw - NP;
    orow = (long)aw * D_ + h * 64 + off;
    if (aw >= NA) {                 // zero the alignment-pad rows
      bf16x8 z;
#pragma unroll
      for (int r = 0; r < 8; ++r) z[r] = 0;
      *(bf16x8*)(t16 + orow) = z;
      return;
    }
    node = aw; q = Aq;
  }

  bf16x8 qv = *(const bf16x8*)(q + (long)node * D_ + h * 64 + off);
  float qf[8];
#pragma unroll
  for (int r = 0; r < 8; ++r) qf[r] = bf2f((unsigned short)qv[r]);

  float res[8] = {};

  auto process = [&](const unsigned short* K, const unsigned short* V,
                     int nodeabs, float ps) {
    int st = starts[nodeabs], dg = degree[nodeabs];
    float m = -INFINITY, l = 0.f;
    float acc[8] = {};
    for (int i = 0; i < dg; ++i) {
      int s = csr[st + i];
      const long ro = (long)s * D_ + h * 64 + off;
      bf16x8 kv = *(const bf16x8*)(K + ro);
      bf16x8 vv = *(const bf16x8*)(V + ro);
      float dot = 0.f;
#pragma unroll
      for (int r = 0; r < 8; ++r)
        dot = fmaf(qf[r], bf2f((unsigned short)kv[r]), dot);
      dot += __shfl_xor(dot, 1);
      dot += __shfl_xor(dot, 2);
      dot += __shfl_xor(dot, 4);
      float sc = dot * ps;
      float mn = fmaxf(m, sc);
      float scale = __expf(m - mn);   // m=-inf first edge -> 0
      float pv = __expf(sc - mn);
      l = l * scale + pv;
#pragma unroll
      for (int r = 0; r < 8; ++r)
        acc[r] = acc[r] * scale + pv * bf2f((unsigned short)vv[r]);
      m = mn;
    }
    if (l > 0.f) {
      float inv = 1.f / l;
#pragma unroll
      for (int r = 0; r < 8; ++r) res[r] += acc[r] * inv;
    }
  };

  float outscale;
  if (paper) {
    process(Akw, Avw, node, pri[h] * 0.125f);
    process(Pkc, Pvc, NP + node, pri[8 + h] * 0.125f);
    outscale = 0.5f;
  } else {
    process(Pkb, Pvb, 2 * NP + node, pri[16 + h] * 0.125f);
    outscale = 1.0f;
  }

  bf16x8 o;
#pragma unroll
  for (int r = 0; r < 8; ++r) o[r] = (short)f2bf(res[r] * outscale);
  *(bf16x8*)(t16 + orow) = o;
}

// ================= MFMA GEMM core (round-6 verified structure) ===============
__device__ __forceinline__ void gload_lds16(const void* g, void* l) {
  __builtin_amdgcn_global_load_lds(
      (const __attribute__((address_space(1))) void*)g,
      (__attribute__((address_space(3))) void*)l, 16, 0, 0);
}

struct ProjArgs {
  const unsigned short *A0, *A1;
  const unsigned short *B0, *B1;
  const float *bias0, *bias1;
  void* outs[8];                    // 0-2 author, 3-7 paper
  int M0, M1, split;                // split = authorMtiles*6
};

__global__ __launch_bounds__(512, 2) void gemm_proj(ProjArgs pa) {
  __shared__ unsigned short Asm[2][256 * 64];
  __shared__ unsigned short Bsm[2][256 * 64];

  const int nwg = gridDim.x, orig = blockIdx.x;
  const int q8 = nwg >> 3, r8 = nwg & 7;
  const int xcd = orig & 7, pos = orig >> 3;
  const int wgid =
      (xcd < r8 ? xcd * (q8 + 1) : r8 * (q8 + 1) + (xcd - r8) * q8) + pos;

  int reg, mt, nt;
  if (wgid < pa.split) { reg = 0; mt = wgid / 6; nt = wgid - mt * 6; }
  else { int r = wgid - pa.split; reg = 1; mt = r / 10; nt = r - mt * 10; }
  const unsigned short* A  = reg ? pa.A1 : pa.A0;
  const unsigned short* Bt = reg ? pa.B1 : pa.B0;
  const float* bias = reg ? pa.bias1 : pa.bias0;
  const int M = reg ? pa.M1 : pa.M0;
  const int bm = mt * 256, bn = nt * 256;

  const int tid = threadIdx.x;
  const int wave = tid >> 6, lane = tid & 63;
  const int wm = (wave >> 2) * 128;
  const int wn = (wave & 3) * 64;
  const int srow = tid >> 3;
  const int swz = ((tid & 7) ^ (srow & 7)) * 8;

  f32x4 acc[8][4] = {};
  const int rr = lane & 15;
  const int rx = (rr & 7) << 4;

  auto STAGE = [&](int buf, int kt) {
    const int k0 = kt * 64;
#pragma unroll
    for (int i = 0; i < 4; ++i) {
      int gr = bm + srow + i * 64;
      if (gr >= M) gr = M - 1;
      gload_lds16(A + (long)gr * D_ + k0 + swz, &Asm[buf][i * 4096 + wave * 512]);
    }
#pragma unroll
    for (int i = 0; i < 4; ++i) {
      int gr = bn + srow + i * 64;
      gload_lds16(Bt + (long)gr * D_ + k0 + swz, &Bsm[buf][i * 4096 + wave * 512]);
    }
  };

  STAGE(0, 0);
  STAGE(1, 1);
#pragma unroll
  for (int t = 0; t < 8; ++t) {
    const int p = t & 1;
    if (t == 7) asm volatile("s_waitcnt vmcnt(0)" ::: "memory");
    else        asm volatile("s_waitcnt vmcnt(8)" ::: "memory");
    __builtin_amdgcn_s_barrier();
    asm volatile("" ::: "memory");

#pragma unroll
    for (int kk = 0; kk < 2; ++kk) {
      const int cb = kk * 64 + (lane >> 4) * 16;
      const int cs = cb ^ rx;
      bf16x8 af[8], bfr[4];
#pragma unroll
      for (int mi = 0; mi < 8; ++mi)
        af[mi] = *(const bf16x8*)((const char*)&Asm[p][0] +
                                  (wm + mi * 16 + rr) * 128 + cs);
#pragma unroll
      for (int nj = 0; nj < 4; ++nj)
        bfr[nj] = *(const bf16x8*)((const char*)&Bsm[p][0] +
                                   (wn + nj * 16 + rr) * 128 + cs);
      __builtin_amdgcn_s_setprio(1);
#pragma unroll
      for (int mi = 0; mi < 8; ++mi)
#pragma unroll
        for (int nj = 0; nj < 4; ++nj)
          acc[mi][nj] = __builtin_amdgcn_mfma_f32_16x16x32_bf16(
              af[mi], bfr[nj], acc[mi][nj], 0, 0, 0);
      __builtin_amdgcn_s_setprio(0);
    }

    asm volatile("" ::: "memory");
    __builtin_amdgcn_s_barrier();
    asm volatile("" ::: "memory");
    if (t + 2 < 8) STAGE(p, t + 2);
  }

  const int cr = (lane >> 4) * 4;
  const int cc = lane & 15;
  const int matu = (bn + wn) >> 9;
  const int wcb = (bn + wn) & 511;
  unsigned short* ob16 = (unsigned short*)pa.outs[(reg ? 3 : 0) + matu];
#pragma unroll
  for (int mi = 0; mi < 8; ++mi) {
    int rowb = bm + wm + mi * 16 + cr;
#pragma unroll
    for (int nj = 0; nj < 4; ++nj) {
      int col = bn + wn + nj * 16 + cc;
      float bb = bias[col];
#pragma unroll
      for (int r = 0; r < 4; ++r) {
        int row = rowb + r;
        if (row >= M) continue;
        float val = acc[mi][nj][r] + bb;
        ob16[(long)row * D_ + wcb + nj * 16 + cc] = f2bf(val);
      }
    }
  }
}

struct OutArgs {
  const unsigned short* A;          // combined t16
  const unsigned short *B0, *B1;
  const float *bias0, *bias1;
  const float *H0, *H1;
  const float* skip;
  float *o0, *o1;
  int mtsplit, NAp, M0, M1;
};

__global__ __launch_bounds__(512, 2) void gemm_out(OutArgs oa) {
  __shared__ unsigned short Asm[2][256 * 64];
  __shared__ unsigned short Bsm[2][256 * 64];

  const int nwg = gridDim.x, orig = blockIdx.x;
  const int q8 = nwg >> 3, r8 = nwg & 7;
  const int xcd = orig & 7, pos = orig >> 3;
  const int wgid =
      (xcd < r8 ? xcd * (q8 + 1) : r8 * (q8 + 1) + (xcd - r8) * q8) + pos;

  const int bmt = wgid >> 1;
  const int bn = (wgid & 1) * 256;
  const int reg = bmt >= oa.mtsplit;
  const int bm = (reg ? bmt - oa.mtsplit : bmt) * 256;   // region-local
  const int abase = reg ? oa.NAp : 0;
  const int M = reg ? oa.M1 : oa.M0;
  const unsigned short* Bt = reg ? oa.B1 : oa.B0;
  const float* bias = reg ? oa.bias1 : oa.bias0;
  const float* Hres = reg ? oa.H1 : oa.H0;
  float* outp = reg ? oa.o1 : oa.o0;

  const int tid = threadIdx.x;
  const int wave = tid >> 6, lane = tid & 63;
  const int wm = (wave >> 2) * 128;
  const int wn = (wave & 3) * 64;
  const int srow = tid >> 3;
  const int swz = ((tid & 7) ^ (srow & 7)) * 8;

  f32x4 acc[8][4] = {};
  const int rr = lane & 15;
  const int rx = (rr & 7) << 4;

  auto STAGE = [&](int buf, int kt) {
    const int k0 = kt * 64;
#pragma unroll
    for (int i = 0; i < 4; ++i) {
      int gr = bm + srow + i * 64;
      if (gr >= M) gr = M - 1;
      gload_lds16(oa.A + (long)(abase + gr) * D_ + k0 + swz,
                  &Asm[buf][i * 4096 + wave * 512]);
    }
#pragma unroll
    for (int i = 0; i < 4; ++i) {
      int gr = bn + srow + i * 64;   // < 512 always
      gload_lds16(Bt + (long)gr * D_ + k0 + swz,
                  &Bsm[buf][i * 4096 + wave * 512]);
    }
  };

  STAGE(0, 0);
  STAGE(1, 1);
#pragma unroll
  for (int t = 0; t < 8; ++t) {
    const int p = t & 1;
    if (t == 7) asm volatile("s_waitcnt vmcnt(0)" ::: "memory");
    else        asm volatile("s_waitcnt vmcnt(8)" ::: "memory");
    __builtin_amdgcn_s_barrier();
    asm volatile("" ::: "memory");

#pragma unroll
    for (int kk = 0; kk < 2; ++kk) {
      const int cb = kk * 64 + (lane >> 4) * 16;
      const int cs = cb ^ rx;
      bf16x8 af[8], bfr[4];
#pragma unroll
      for (int mi = 0; mi < 8; ++mi)
        af[mi] = *(const bf16x8*)((const char*)&Asm[p][0] +
                                  (wm + mi * 16 + rr) * 128 + cs);
#pragma unroll
      for (int nj = 0; nj < 4; ++nj)
        bfr[nj] = *(const bf16x8*)((const char*)&Bsm[p][0] +
                                   (wn + nj * 16 + rr) * 128 + cs);
      __builtin_amdgcn_s_setprio(1);
#pragma unroll
      for (int mi = 0; mi < 8; ++mi)
#pragma unroll
        for (int nj = 0; nj < 4; ++nj)
          acc[mi][nj] = __builtin_amdgcn_mfma_f32_16x16x32_bf16(
              af[mi], bfr[nj], acc[mi][nj], 0, 0, 0);
      __builtin_amdgcn_s_setprio(0);
    }

    asm volatile("" ::: "memory");
    __builtin_amdgcn_s_barrier();
    asm volatile("" ::: "memory");
    if (t + 2 < 8) STAGE(p, t + 2);
  }

  float sv = oa.skip[reg];
  float alpha = 1.f / (1.f + expf(-sv));
  float beta = 1.f - alpha;
  const int cr = (lane >> 4) * 4;
  const int cc = lane & 15;
#pragma unroll
  for (int mi = 0; mi < 8; ++mi) {
    int rowb = bm + wm + mi * 16 + cr;
#pragma unroll
    for (int nj = 0; nj < 4; ++nj) {
      int col = bn + wn + nj * 16 + cc;
      float bb = bias[col];
#pragma unroll
      for (int r = 0; r < 4; ++r) {
        int row = rowb + r;
        if (row >= M) continue;
        float val = acc[mi][nj][r] + bb;
        val = val * alpha + Hres[(long)row * D_ + col] * beta;
        outp[(long)row * D_ + col] = val;
      }
    }
  }
}

// ================= launch =====================================================
extern "C" void kernel_launch(void* const* d_in, const int* in_sizes, int n_in,
                              void* d_out, int out_size, void* d_ws, size_t ws_size,
                              hipStream_t stream) {
  const float* h_author = (const float*)d_in[0];
  const float* h_paper  = (const float*)d_in[1];
  const int* w_src = (const int*)d_in[2];
  const int* w_dst = (const int*)d_in[3];
  const int* c_src = (const int*)d_in[4];
  const int* c_dst = (const int*)d_in[5];
  const int* b_src = (const int*)d_in[6];
  const int* b_dst = (const int*)d_in[7];
  const float* Wk = (const float*)d_in[8];
  const float* bk = (const float*)d_in[9];
  const float* Wq = (const float*)d_in[10];
  const float* bq = (const float*)d_in[11];
  const float* Wv = (const float*)d_in[12];
  const float* bv = (const float*)d_in[13];
  const float* Wa = (const float*)d_in[14];
  const float* ba = (const float*)d_in[15];
  const float* rel_att = (const float*)d_in[16];
  const float* rel_msg = (const float*)d_in[17];
  const float* rel_pri = (const float*)d_in[18];
  const float* skip = (const float*)d_in[19];

  const int NA = in_sizes[0] / D_;
  const int NP = in_sizes[1] / D_;
  const int E  = in_sizes[2];
  const int NT = 2 * NP + NA;
  const int tA = (NA + 255) / 256;       // author M tiles
  const int tP = (NP + 255) / 256;       // paper M tiles
  const int NAp = tA * 256;              // aligned author row count

  char* w = (char*)d_ws;
  auto alloc = [&](long bytes) {
    char* p = w;
    w += (bytes + 255) & ~255L;
    return p;
  };
  unsigned short* hA16 = (unsigned short*)alloc((long)NA * D_ * 2);
  unsigned short* hP16 = (unsigned short*)alloc((long)NP * D_ * 2);
  unsigned short* Pq   = (unsigned short*)alloc((long)NP * D_ * 2);
  unsigned short* Pkc  = (unsigned short*)alloc((long)NP * D_ * 2);
  unsigned short* Pvc  = (unsigned short*)alloc((long)NP * D_ * 2);
  unsigned short* Pkb  = (unsigned short*)alloc((long)NP * D_ * 2);
  unsigned short* Pvb  = (unsigned short*)alloc((long)NP * D_ * 2);
  unsigned short* Aq   = (unsigned short*)alloc((long)NA * D_ * 2);
  unsigned short* Akw  = (unsigned short*)alloc((long)NA * D_ * 2);
  unsigned short* Avw  = (unsigned short*)alloc((long)NA * D_ * 2);
  unsigned short* t16  = (unsigned short*)alloc((long)(NAp + NP) * D_ * 2);
  unsigned short* BtP  = (unsigned short*)alloc((long)2560 * D_ * 2);
  unsigned short* BtA  = (unsigned short*)alloc((long)1536 * D_ * 2);
  float* bfP           = (float*)alloc(2560 * 4);
  float* bfA           = (float*)alloc(1536 * 4);
  unsigned short* Wa0t = (unsigned short*)alloc((long)D_ * D_ * 2);
  unsigned short* Wa1t = (unsigned short*)alloc((long)D_ * D_ * 2);
  int* degree          = (int*)alloc((long)NT * 4);
  int* starts          = (int*)alloc((long)NT * 4);
  int* cursor          = (int*)alloc((long)NT * 4);
  int* csr             = (int*)alloc((long)3 * E * 4);
  int* aux             = (int*)alloc(((long)NT / 256 + 2) * 4);

  const long WD = (long)D_ * D_;
  const long RS = (long)H_ * 64 * 64;
  const long SEG = (long)D_ * D_;

  float* out_a = (float*)d_out;
  float* out_p = out_a + (long)NA * D_;

  // ---- 1 dispatch: all precompute ----
  {
    PrepArgs p;
    p.hA = h_author; p.hP = h_paper; p.hA16 = hA16; p.hP16 = hP16;
    // fuse jobs 0-3: paper Bt segments; 4-5: author Bt segments
    p.fWin[0] = Wk + WD; p.fbin[0] = bk + D_; p.frel[0] = rel_att + RS;
    p.fWf[0] = BtP + SEG;     p.fbf[0] = bfP + 512;
    p.fWin[1] = Wv + WD; p.fbin[1] = bv + D_; p.frel[1] = rel_msg + RS;
    p.fWf[1] = BtP + 2 * SEG; p.fbf[1] = bfP + 1024;
    p.fWin[2] = Wk + WD; p.fbin[2] = bk + D_; p.frel[2] = rel_att + 2 * RS;
    p.fWf[2] = BtP + 3 * SEG; p.fbf[2] = bfP + 1536;
    p.fWin[3] = Wv + WD; p.fbin[3] = bv + D_; p.frel[3] = rel_msg + 2 * RS;
    p.fWf[3] = BtP + 4 * SEG; p.fbf[3] = bfP + 2048;
    p.fWin[4] = Wk;      p.fbin[4] = bk;      p.frel[4] = rel_att;
    p.fWf[4] = BtA + SEG;     p.fbf[4] = bfA + 512;
    p.fWin[5] = Wv;      p.fbin[5] = bv;      p.frel[5] = rel_msg;
    p.fWf[5] = BtA + 2 * SEG; p.fbf[5] = bfA + 1024;
    p.tW[0] = Wq + WD; p.tWt[0] = BtP;
    p.tW[1] = Wq;      p.tWt[1] = BtA;
    p.tW[2] = Wa;      p.tWt[2] = Wa0t;
    p.tW[3] = Wa + WD; p.tWt[3] = Wa1t;
    p.cin[0] = bq + D_; p.cout[0] = bfP;
    p.cin[1] = bq;      p.cout[1] = bfA;
    p.degree = degree; p.NT = NT;
    p.b1 = NA / 8;
    p.b2 = p.b1 + NP / 8;
    p.b3 = p.b2 + 6 * 513;
    p.b4 = p.b3 + 4 * 512;
    p.b5 = p.b4 + 2;
    int total = p.b5 + (NT + 511) / 512;
    prep_kernel<<<total, 512, 0, stream>>>(p);
  }

  // ---- CSR build ----
  {
    int th = 3 * E;
    hist_kernel<<<(th + 255) / 256, 256, 0, stream>>>(w_dst, c_dst, b_dst,
                                                      degree, E, NP);
    int nb = (NT + 255) / 256;
    scan1_kernel<<<nb, 256, 0, stream>>>(degree, starts, aux, NT);
    scan2_kernel<<<1, 1024, 0, stream>>>(aux, nb);
    scan3_kernel<<<nb, 256, 0, stream>>>(starts, cursor, aux, NT);
    scatter_kernel<<<(th + 255) / 256, 256, 0, stream>>>(
        w_src, w_dst, c_src, c_dst, b_src, b_dst, cursor, csr, E, NP);
  }

  // ---- 1 dispatch: both projection GEMMs ----
  {
    ProjArgs pa;
    pa.A0 = hA16; pa.A1 = hP16;
    pa.B0 = BtA;  pa.B1 = BtP;
    pa.bias0 = bfA; pa.bias1 = bfP;
    pa.outs[0] = Aq;  pa.outs[1] = Akw; pa.outs[2] = Avw;
    pa.outs[3] = Pq;  pa.outs[4] = Pkc; pa.outs[5] = Pvc;
    pa.outs[6] = Pkb; pa.outs[7] = Pvb;
    pa.M0 = NA; pa.M1 = NP;
    pa.split = tA * 6;
    int nwg = pa.split + tP * 10;
    gemm_proj<<<nwg, 512, 0, stream>>>(pa);
  }

  // ---- 1 dispatch: all edge attention (papers: writes+cites; authors: wb) ----
  {
    long th = (long)(NP + NAp) * 64;
    attn_all<<<(int)((th + 255) / 256), 256, 0, stream>>>(
        Pq, Akw, Avw, Pkc, Pvc, Aq, Pkb, Pvb,
        csr, starts, degree, rel_pri, t16, NP, NA, NAp);
  }

  // ---- 1 dispatch: both output GEMMs (skip-mix epilogue) ----
  {
    OutArgs oa;
    oa.A = t16;
    oa.B0 = Wa0t; oa.B1 = Wa1t;
    oa.bias0 = ba; oa.bias1 = ba + D_;
    oa.H0 = h_author; oa.H1 = h_paper;
    oa.skip = skip;
    oa.o0 = out_a; oa.o1 = out_p;
    oa.mtsplit = tA; oa.NAp = NAp; oa.M0 = NA; oa.M1 = NP;
    int nwg = (tA + tP) * 2;
    gemm_out<<<nwg, 512, 0, stream>>>(oa);
  }
}